// Round 2
// baseline (274.235 us; speedup 1.0000x reference)
//
#include <hip/hip_runtime.h>
#include <stdint.h>
#include <math.h>

#define NDIM 256
#define BATCH 65536
#define NROT 32640          // 256*255/2

typedef float  f32x4 __attribute__((ext_vector_type(4)));
typedef short  s16x8 __attribute__((ext_vector_type(8)));
typedef unsigned int u32x4 __attribute__((ext_vector_type(4)));
typedef unsigned int u32x2 __attribute__((ext_vector_type(2)));

// round-to-nearest-even float -> bf16 bits
static __device__ __forceinline__ unsigned short f2bf(float f) {
    unsigned int u = __float_as_uint(f);
    u += 0x7fffu + ((u >> 16) & 1u);
    return (unsigned short)(u >> 16);
}
static __device__ __forceinline__ float bf2f(unsigned short h) {
    return __uint_as_float(((unsigned)h) << 16);
}

// split 4 fp32 -> bf16 hi + bf16 lo (packed).  a ~= hi + lo, |err| ~ 2^-18|a|
static __device__ __forceinline__ void split4(f32x4 v, u32x2* hi, u32x2* lo) {
    unsigned short h[4], l[4];
    #pragma unroll
    for (int i = 0; i < 4; i++) {
        h[i] = f2bf(v[i]);
        l[i] = f2bf(v[i] - bf2f(h[i]));
    }
    *hi = (u32x2){ (unsigned)h[0] | ((unsigned)h[1] << 16),
                   (unsigned)h[2] | ((unsigned)h[3] << 16) };
    *lo = (u32x2){ (unsigned)l[0] | ((unsigned)l[1] << 16),
                   (unsigned)l[2] | ((unsigned)l[3] << 16) };
}
static __device__ __forceinline__ void split8(const float* v, u32x4* hi, u32x4* lo) {
    unsigned short h[8], l[8];
    #pragma unroll
    for (int i = 0; i < 8; i++) {
        h[i] = f2bf(v[i]);
        l[i] = f2bf(v[i] - bf2f(h[i]));
    }
    *hi = (u32x4){ (unsigned)h[0] | ((unsigned)h[1] << 16),
                   (unsigned)h[2] | ((unsigned)h[3] << 16),
                   (unsigned)h[4] | ((unsigned)h[5] << 16),
                   (unsigned)h[6] | ((unsigned)h[7] << 16) };
    *lo = (u32x4){ (unsigned)l[0] | ((unsigned)l[1] << 16),
                   (unsigned)l[2] | ((unsigned)l[3] << 16),
                   (unsigned)l[4] | ((unsigned)l[5] << 16),
                   (unsigned)l[6] | ((unsigned)l[7] << 16) };
}

// nearest 4-aligned sweep boundary to k*(NROT/pblk); shared by k_blocks
// and k_combine (the block-diagonal skip logic depends on agreement).
static __device__ __forceinline__ int sweep_bound(int k, int pblk) {
    int target = k * (NROT / pblk);
    int best = 0, bd = 0x7fffffff;
    for (int i = 0; i <= 256; i += 4) {
        int pre = i * 255 - (i * (i - 1)) / 2;
        int d = pre - target; d = (d < 0) ? -d : d;
        if (d < bd) { bd = d; best = i; }
    }
    return best;
}

// ---------------- kernel 0: angle table (cos,sin) for both rot sets ---------
// Hoists all sincosf out of the latency-bound k_blocks into a fully parallel
// kernel (65280 threads, one sincosf each). Table layout: cs[set*NROT + r].
__global__ __launch_bounds__(256) void k_cs(const float* __restrict__ r1,
                                            const float* __restrict__ r2,
                                            float2* __restrict__ cs) {
    int i = blockIdx.x * 256 + threadIdx.x;          // 0 .. 2*NROT-1
    float th = (i < NROT) ? r1[i] : r2[i - NROT];
    float sv, cv; sincosf(th, &sv, &cv);
    cs[i] = make_float2(cv, sv);
}

// ---------------- kernel 1: build pblk partial Givens products per matrix ---
// 4 sweeps fused (skewed schedule, order-equivalent: disjoint-row rotations
// commute). Active rows u0..u3 in registers. Angles come from the
// precomputed cs table (coalesced float2 loads, 4-way unrolled) -- no trig
// on the latency-critical wave. Identity padding keeps the steady loop
// guard-free with a fixed unroll-8 body.
__global__ __launch_bounds__(64) void k_blocks(const float2* __restrict__ cs,
                                               float* __restrict__ bmats, int pblk) {
    __shared__ float colb[264 * 64];
    __shared__ float2 csb[256 * 4];     // one group's steady angles, [jj][a]
    __shared__ float2 tri[24 * 6];      // all groups' triangle angles

    const int t = threadIdx.x;          // column within chunk
    const int bid = blockIdx.x;
    const int chunk = bid & 3;          // 0..3 (64 cols each)
    const int b = (bid >> 2) % pblk;    // 0..pblk-1
    const int set = (bid >> 2) / pblk;  // 0 = rots1, 1 = rots2
    const int col0 = chunk * 64;
    const float2* cst = cs + (size_t)set * NROT;

    const int s0 = sweep_bound(b, pblk);
    const int s1 = sweep_bound(b + 1, pblk);
    const int ngroups = (s1 - s0) >> 2;

    // zero colb (incl. pad rows 256..263), set identity diagonal
    {
        const f32x4 z = {0.f, 0.f, 0.f, 0.f};
        #pragma unroll 11
        for (int q = 0; q < 66; q++)
            *(f32x4*)&colb[(q * 64 + t) * 4] = z;
        colb[(col0 + t) * 64 + t] = 1.0f;
    }

    // stage all triangle angles (6 per group) into LDS
    for (int k = t; k < ngroups * 6; k += 64) {
        int g = k / 6, q = k - g * 6;
        int a  = (q < 3) ? 0 : ((q < 5) ? 1 : 2);
        int bb = (q < 3) ? (q + 1) : ((q < 5) ? (q - 1) : 3);
        int m0 = s0 + g * 4;
        int m = m0 + a;
        int base = m * 255 - (m * (m - 1)) / 2;
        tri[k] = cst[base - m - 1 + m0 + bb];
    }
    // single-wave WG: DS pipe is in-order per wave, no barrier needed

    for (int g = 0; g < ngroups; g++) {
        const int m0 = s0 + g * 4;
        int off[4];
        #pragma unroll
        for (int a = 0; a < 4; a++) {
            int m = m0 + a;
            int base = m * 255 - (m * (m - 1)) / 2;
            off[a] = base - m - 1;                  // angle for (m,j) = cst[off[a]+j]
        }
        const int n_j = 252 - m0;
        const int n_p = (n_j > 0) ? ((n_j + 7) & ~7) : 0;

        // stage steady angles with identity padding: csb[jj*4 + a]
        // fixed 16-iter guarded loop, unrolled 4 -> 4 global loads in flight
        {
            const int kmax = n_p * 4;
            #pragma unroll 4
            for (int it = 0; it < 16; it++) {
                int k = t + it * 64;
                if (k < kmax) {
                    int jj = k >> 2, a = k & 3;
                    int j = m0 + 4 + jj;
                    csb[k] = (j < 256) ? cst[off[a] + j] : make_float2(1.f, 0.f);
                }
            }
        }

        // active rows -> registers
        float u0 = colb[(m0 + 0) * 64 + t];
        float u1 = colb[(m0 + 1) * 64 + t];
        float u2 = colb[(m0 + 2) * 64 + t];
        float u3 = colb[(m0 + 3) * 64 + t];

        // triangle peel: (m0,m0+1..3), (m0+1,m0+2..3), (m0+2,m0+3)
        {
            float2 cv; float nr;
            cv = tri[g * 6 + 0]; nr = cv.y * u0 + cv.x * u1; u0 = cv.x * u0 - cv.y * u1; u1 = nr;
            cv = tri[g * 6 + 1]; nr = cv.y * u0 + cv.x * u2; u0 = cv.x * u0 - cv.y * u2; u2 = nr;
            cv = tri[g * 6 + 2]; nr = cv.y * u0 + cv.x * u3; u0 = cv.x * u0 - cv.y * u3; u3 = nr;
            cv = tri[g * 6 + 3]; nr = cv.y * u1 + cv.x * u2; u1 = cv.x * u1 - cv.y * u2; u2 = nr;
            cv = tri[g * 6 + 4]; nr = cv.y * u1 + cv.x * u3; u1 = cv.x * u1 - cv.y * u3; u3 = nr;
            cv = tri[g * 6 + 5]; nr = cv.y * u2 + cv.x * u3; u2 = cv.x * u2 - cv.y * u3; u3 = nr;
        }

        // steady state: guard-free, unroll 8, 8-deep row prefetch
        if (n_p > 0) {
            float rbuf[8];
            #pragma unroll
            for (int p = 0; p < 8; p++)
                rbuf[p] = colb[(m0 + 4 + p) * 64 + t];
            for (int c = 0; c < n_p; c += 8) {
                #pragma unroll
                for (int p = 0; p < 8; p++) {
                    const int j = m0 + 4 + c + p;
                    float r = rbuf[p];
                    int jn = j + 8; jn = (jn < 263) ? jn : 263;
                    rbuf[p] = colb[jn * 64 + t];
                    float2 a0 = csb[(c + p) * 4 + 0];
                    float2 a1 = csb[(c + p) * 4 + 1];
                    float2 a2 = csb[(c + p) * 4 + 2];
                    float2 a3 = csb[(c + p) * 4 + 3];
                    float nr;
                    nr = a0.y * u0 + a0.x * r; u0 = a0.x * u0 - a0.y * r; r = nr;
                    nr = a1.y * u1 + a1.x * r; u1 = a1.x * u1 - a1.y * r; r = nr;
                    nr = a2.y * u2 + a2.x * r; u2 = a2.x * u2 - a2.y * r; r = nr;
                    nr = a3.y * u3 + a3.x * r; u3 = a3.x * u3 - a3.y * r; r = nr;
                    colb[j * 64 + t] = r;
                }
            }
        }
        colb[(m0 + 0) * 64 + t] = u0;
        colb[(m0 + 1) * 64 + t] = u1;
        colb[(m0 + 2) * 64 + t] = u2;
        colb[(m0 + 3) * 64 + t] = u3;
    }

    float* outm = bmats + (size_t)(set * pblk + b) * 65536;
    for (int r = 0; r < 256; r++)
        outm[(size_t)r * 256 + col0 + t] = colb[r * 64 + t];
}

// ---------------- kernel 2: pairwise combine round (bf16x3 MFMA matmul) -----
// dst[p] = src[2p+1] @ src[2p], fp32 in/out, computed as
// D = Ahi*Bhi + Ahi*Blo + Alo*Bhi with fp32 MFMA accumulators.
// Block-diagonal skip logic (copy tiles / kb0) identical to fp32 version.
// Round 1 additionally carries the xnorm WGs (blockIdx.y >= 2*half): this
// kernel has 20 KB LDS -> ~8 WGs/CU, so the x -> xbf bf16 stream runs at
// high occupancy overlapped with the MFMA tiles (vs 2 WGs/CU when it was
// fused into the 77 KB-LDS k_blocks).
__global__ __launch_bounds__(256) void k_combine(const float* __restrict__ src,
                                                 float* __restrict__ dst,
                                                 int half, int pblk,
                                                 const float* __restrict__ xg,
                                                 unsigned short* __restrict__ xbf) {
    const int by = blockIdx.y;
    const int tid = threadIdx.x;

    if (by >= 2 * half) {                      // ---- fused xnorm WGs ----
        const int id = (by - 2 * half) * 16 + blockIdx.x;   // 0..1023
        const int w = tid >> 6, lane = tid & 63;
        const int r0 = id * 64;
        #pragma unroll 2
        for (int p = 0; p < 16; p++) {
            int row = r0 + p * 4 + w;
            f32x4 v = *(const f32x4*)&xg[(size_t)row * 256 + lane * 4];
            float s = v[0] * v[0] + v[1] * v[1] + v[2] * v[2] + v[3] * v[3];
            #pragma unroll
            for (int off = 32; off; off >>= 1) s += __shfl_xor(s, off, 64);
            float sc = 1.0f / sqrtf(s);
            unsigned short h0 = f2bf(v[0] * sc), h1 = f2bf(v[1] * sc);
            unsigned short h2 = f2bf(v[2] * sc), h3 = f2bf(v[3] * sc);
            u32x2 pk = { (unsigned)h0 | ((unsigned)h1 << 16),
                         (unsigned)h2 | ((unsigned)h3 << 16) };
            *(u32x2*)&xbf[(size_t)row * 256 + lane * 4] = pk;
        }
        return;
    }

    const int set = by / half, pidx = by % half;
    const int stride = pblk / (2 * half);
    const int s0A = sweep_bound((2 * pidx + 1) * stride, pblk);
    const float* Am = src + (size_t)(set * 2 * half + 2 * pidx + 1) * 65536;
    const float* Bm = src + (size_t)(set * 2 * half + 2 * pidx) * 65536;
    float* Dm = dst + (size_t)(set * half + pidx) * 65536;
    const int tr = blockIdx.x >> 2, tc = blockIdx.x & 3;

    if (tr * 64 + 64 <= s0A) {                 // pure copy tile: D = B
        #pragma unroll
        for (int it = 0; it < 4; it++) {
            int flat = tid + it * 256;
            int r = flat >> 4, c4 = flat & 15;
            size_t idx = (size_t)(tr * 64 + r) * 256 + tc * 64 + c4 * 4;
            *(f32x4*)&Dm[idx] = *(const f32x4*)&Bm[idx];
        }
        return;
    }
    const int kb0 = (tr * 64 >= s0A) ? (s0A >> 5) : 0;

    __shared__ unsigned short Ahi[64 * 40], Alo[64 * 40];
    __shared__ unsigned short Bhi[64 * 40], Blo[64 * 40];

    const int lane = tid & 63, w = tid >> 6;
    const int mh = (w >> 1) * 32, nh = (w & 1) * 32;
    const int l15 = lane & 15, lq = lane >> 4;
    const int bn = tid & 63, bkq = tid >> 6;   // B transpose-stage mapping

    f32x4 acc[2][2];
    #pragma unroll
    for (int i = 0; i < 2; i++)
        #pragma unroll
        for (int j = 0; j < 2; j++) acc[i][j] = (f32x4){0.f, 0.f, 0.f, 0.f};

    for (int kb = kb0; kb < 8; kb++) {
        __syncthreads();
        // A stage: 64 rows x 32 k, natural k-minor layout
        #pragma unroll
        for (int it = 0; it < 2; it++) {
            int flat = tid + it * 256;
            int r = flat >> 3, c4 = flat & 7;
            f32x4 v = *(const f32x4*)&Am[(size_t)(tr * 64 + r) * 256 + kb * 32 + c4 * 4];
            u32x2 hi, lo; split4(v, &hi, &lo);
            *(u32x2*)&Ahi[r * 40 + c4 * 4] = hi;
            *(u32x2*)&Alo[r * 40 + c4 * 4] = lo;
        }
        // B stage: transpose [32k][64n] -> [64n][32k] via coalesced re-reads
        {
            float bv[8];
            #pragma unroll
            for (int i = 0; i < 8; i++)
                bv[i] = Bm[(size_t)(kb * 32 + bkq * 8 + i) * 256 + tc * 64 + bn];
            u32x4 hi, lo; split8(bv, &hi, &lo);
            *(u32x4*)&Bhi[bn * 40 + bkq * 8] = hi;
            *(u32x4*)&Blo[bn * 40 + bkq * 8] = lo;
        }
        __syncthreads();
        s16x8 ah[2], al[2], bh[2], bl[2];
        #pragma unroll
        for (int tm = 0; tm < 2; tm++) {
            ah[tm] = *(const s16x8*)&Ahi[(mh + tm * 16 + l15) * 40 + lq * 8];
            al[tm] = *(const s16x8*)&Alo[(mh + tm * 16 + l15) * 40 + lq * 8];
        }
        #pragma unroll
        for (int tn = 0; tn < 2; tn++) {
            bh[tn] = *(const s16x8*)&Bhi[(nh + tn * 16 + l15) * 40 + lq * 8];
            bl[tn] = *(const s16x8*)&Blo[(nh + tn * 16 + l15) * 40 + lq * 8];
        }
        #pragma unroll
        for (int tm = 0; tm < 2; tm++)
            #pragma unroll
            for (int tn = 0; tn < 2; tn++) {
                acc[tm][tn] = __builtin_amdgcn_mfma_f32_16x16x32_bf16(ah[tm], bh[tn], acc[tm][tn], 0, 0, 0);
                acc[tm][tn] = __builtin_amdgcn_mfma_f32_16x16x32_bf16(ah[tm], bl[tn], acc[tm][tn], 0, 0, 0);
                acc[tm][tn] = __builtin_amdgcn_mfma_f32_16x16x32_bf16(al[tm], bh[tn], acc[tm][tn], 0, 0, 0);
            }
    }
    // epilogue: C/D layout col = lane&15, row = (lane>>4)*4 + reg
    #pragma unroll
    for (int tm = 0; tm < 2; tm++)
        #pragma unroll
        for (int tn = 0; tn < 2; tn++)
            #pragma unroll
            for (int r = 0; r < 4; r++)
                Dm[(size_t)(tr * 64 + mh + tm * 16 + lq * 4 + r) * 256
                   + tc * 64 + nh + tn * 16 + l15] = acc[tm][tn][r];
}

// ---------------- kernel 3: AT/BT = M2 @ diag(cos|sin(phases)) @ M1 -> bf16 -
__global__ __launch_bounds__(256) void k_abt(const float* __restrict__ mats,
                                             const float* __restrict__ phases,
                                             unsigned short* __restrict__ abt) {
    const float* Am = mats + 65536;    // M2
    const float* Bm = mats;            // M1
    const int v = blockIdx.y;          // 0: cos (AT), 1: sin (BT)
    const int tr = blockIdx.x >> 2, tc = blockIdx.x & 3;
    const int tid = threadIdx.x;

    __shared__ unsigned short Ahi[64 * 40], Alo[64 * 40];
    __shared__ unsigned short Bhi[64 * 40], Blo[64 * 40];

    const int lane = tid & 63, w = tid >> 6;
    const int mh = (w >> 1) * 32, nh = (w & 1) * 32;
    const int l15 = lane & 15, lq = lane >> 4;
    const int bn = tid & 63, bkq = tid >> 6;

    f32x4 acc[2][2];
    #pragma unroll
    for (int i = 0; i < 2; i++)
        #pragma unroll
        for (int j = 0; j < 2; j++) acc[i][j] = (f32x4){0.f, 0.f, 0.f, 0.f};

    for (int kb = 0; kb < 8; kb++) {
        __syncthreads();
        #pragma unroll
        for (int it = 0; it < 2; it++) {
            int flat = tid + it * 256;
            int r = flat >> 3, c4 = flat & 7;
            f32x4 vv = *(const f32x4*)&Am[(size_t)(tr * 64 + r) * 256 + kb * 32 + c4 * 4];
            u32x2 hi, lo; split4(vv, &hi, &lo);
            *(u32x2*)&Ahi[r * 40 + c4 * 4] = hi;
            *(u32x2*)&Alo[r * 40 + c4 * 4] = lo;
        }
        {
            float bv[8];
            #pragma unroll
            for (int i = 0; i < 8; i++) {
                int kg = kb * 32 + bkq * 8 + i;          // wave-uniform k index
                float ph = phases[kg];
                float sc = v ? sinf(ph) : cosf(ph);
                bv[i] = Bm[(size_t)kg * 256 + tc * 64 + bn] * sc;
            }
            u32x4 hi, lo; split8(bv, &hi, &lo);
            *(u32x4*)&Bhi[bn * 40 + bkq * 8] = hi;
            *(u32x4*)&Blo[bn * 40 + bkq * 8] = lo;
        }
        __syncthreads();
        s16x8 ah[2], al[2], bh[2], bl[2];
        #pragma unroll
        for (int tm = 0; tm < 2; tm++) {
            ah[tm] = *(const s16x8*)&Ahi[(mh + tm * 16 + l15) * 40 + lq * 8];
            al[tm] = *(const s16x8*)&Alo[(mh + tm * 16 + l15) * 40 + lq * 8];
        }
        #pragma unroll
        for (int tn = 0; tn < 2; tn++) {
            bh[tn] = *(const s16x8*)&Bhi[(nh + tn * 16 + l15) * 40 + lq * 8];
            bl[tn] = *(const s16x8*)&Blo[(nh + tn * 16 + l15) * 40 + lq * 8];
        }
        #pragma unroll
        for (int tm = 0; tm < 2; tm++)
            #pragma unroll
            for (int tn = 0; tn < 2; tn++) {
                acc[tm][tn] = __builtin_amdgcn_mfma_f32_16x16x32_bf16(ah[tm], bh[tn], acc[tm][tn], 0, 0, 0);
                acc[tm][tn] = __builtin_amdgcn_mfma_f32_16x16x32_bf16(ah[tm], bl[tn], acc[tm][tn], 0, 0, 0);
                acc[tm][tn] = __builtin_amdgcn_mfma_f32_16x16x32_bf16(al[tm], bh[tn], acc[tm][tn], 0, 0, 0);
            }
    }
    #pragma unroll
    for (int tm = 0; tm < 2; tm++)
        #pragma unroll
        for (int tn = 0; tn < 2; tn++)
            #pragma unroll
            for (int r = 0; r < 4; r++)
                abt[(size_t)(v * 256 + tr * 64 + mh + tm * 16 + lq * 4 + r) * 256
                    + tc * 64 + nh + tn * 16 + l15] = f2bf(acc[tm][tn][r]);
}

// ---------------- kernel 4b: per-row 1/||x|| (fallback path) ----------------
__global__ __launch_bounds__(256) void k_norm(const float* __restrict__ x,
                                              float* __restrict__ invn) {
    const int row = blockIdx.x * 4 + (threadIdx.x >> 6);
    const int lane = threadIdx.x & 63;
    f32x4 v = *(const f32x4*)&x[(size_t)row * 256 + lane * 4];
    float s = v[0] * v[0] + v[1] * v[1] + v[2] * v[2] + v[3] * v[3];
    for (int off = 32; off; off >>= 1) s += __shfl_xor(s, off, 64);
    if (lane == 0) invn[row] = 1.0f / sqrtf(s);
}

// ---------------- kernel 5a: GEMM + |.|^2 from pre-converted bf16 x ---------
#define BKP 136   // padded LDS k-stride (bf16 elems)
__global__ __launch_bounds__(256) void k_gemm_bf(const unsigned short* __restrict__ xbf,
                                                 const unsigned short* __restrict__ abt,
                                                 float* __restrict__ out) {
    __shared__ unsigned short As[128 * BKP];
    __shared__ unsigned short Bs[128 * BKP];
    const int tid = threadIdx.x;
    const int cb = blockIdx.x;          // 0..3  (64 out-cols each)
    const int rb = blockIdx.y;          // 0..511
    const int lane = tid & 63, w = tid >> 6;

    f32x4 acc[16];
    #pragma unroll
    for (int i = 0; i < 16; i++) acc[i] = (f32x4){0.f, 0.f, 0.f, 0.f};

    int rA[8], cA[8], grB[8];
    #pragma unroll
    for (int it = 0; it < 8; it++) {
        int flat = tid + it * 256;
        rA[it] = flat >> 4; cA[it] = flat & 15;
        int r = rA[it];
        grB[it] = (r < 64) ? (cb * 64 + r) : (256 + cb * 64 + (r - 64));
    }

    u32x4 pa[8], pb[8];
    #pragma unroll
    for (int it = 0; it < 8; it++) {
        pa[it] = *(const u32x4*)&xbf[(size_t)(rb * 128 + rA[it]) * 256 + cA[it] * 8];
        pb[it] = *(const u32x4*)&abt[(size_t)grB[it] * 256 + cA[it] * 8];
    }
    #pragma unroll
    for (int it = 0; it < 8; it++) {
        *(u32x4*)&As[rA[it] * BKP + cA[it] * 8] = pa[it];
        *(u32x4*)&Bs[rA[it] * BKP + cA[it] * 8] = pb[it];
    }
    __syncthreads();
    #pragma unroll
    for (int it = 0; it < 8; it++) {
        pa[it] = *(const u32x4*)&xbf[(size_t)(rb * 128 + rA[it]) * 256 + 128 + cA[it] * 8];
        pb[it] = *(const u32x4*)&abt[(size_t)grB[it] * 256 + 128 + cA[it] * 8];
    }

    auto compute = [&]() {
        #pragma unroll
        for (int ks = 0; ks < 4; ks++) {
            const int k0 = ks * 32 + (lane >> 4) * 8;
            s16x8 a[2], b[8];
            #pragma unroll
            for (int tm = 0; tm < 2; tm++)
                a[tm] = *(const s16x8*)&As[(w * 32 + tm * 16 + (lane & 15)) * BKP + k0];
            #pragma unroll
            for (int tn = 0; tn < 8; tn++)
                b[tn] = *(const s16x8*)&Bs[(tn * 16 + (lane & 15)) * BKP + k0];
            #pragma unroll
            for (int tm = 0; tm < 2; tm++)
                #pragma unroll
                for (int tn = 0; tn < 8; tn++)
                    acc[tm * 8 + tn] = __builtin_amdgcn_mfma_f32_16x16x32_bf16(
                        a[tm], b[tn], acc[tm * 8 + tn], 0, 0, 0);
        }
    };
    compute();                 // kb=0
    __syncthreads();
    #pragma unroll
    for (int it = 0; it < 8; it++) {
        *(u32x4*)&As[rA[it] * BKP + cA[it] * 8] = pa[it];
        *(u32x4*)&Bs[rA[it] * BKP + cA[it] * 8] = pb[it];
    }
    __syncthreads();
    compute();                 // kb=1

    const int qr = lane >> 4, c = lane & 15;
    #pragma unroll
    for (int tm = 0; tm < 2; tm++) {
        #pragma unroll
        for (int tn = 0; tn < 4; tn++) {
            f32x4 p = acc[tm * 8 + tn];
            f32x4 q = acc[tm * 8 + tn + 4];
            #pragma unroll
            for (int r = 0; r < 4; r++) {
                int m = w * 32 + tm * 16 + qr * 4 + r;
                out[(size_t)(rb * 128 + m) * 256 + cb * 64 + tn * 16 + c] =
                    p[r] * p[r] + q[r] * q[r];
            }
        }
    }
}

// ---------------- kernel 5b: GEMM + |.|^2 from fp32 x (fallback) ------------
__global__ __launch_bounds__(256) void k_gemm_f32(const float* __restrict__ x,
                                                  const unsigned short* __restrict__ abt,
                                                  const float* __restrict__ invn,
                                                  float* __restrict__ out) {
    __shared__ unsigned short As[128 * BKP];
    __shared__ unsigned short Bs[128 * BKP];
    const int tid = threadIdx.x;
    const int cb = blockIdx.x;
    const int rb = blockIdx.y;
    const int lane = tid & 63, w = tid >> 6;

    f32x4 acc[16];
    #pragma unroll
    for (int i = 0; i < 16; i++) acc[i] = (f32x4){0.f, 0.f, 0.f, 0.f};

    for (int kb = 0; kb < 2; kb++) {
        __syncthreads();
        #pragma unroll
        for (int it = 0; it < 16; it++) {
            int flat = tid + it * 256;
            int r = flat >> 5, c4 = flat & 31;
            f32x4 v = *(const f32x4*)&x[(size_t)(rb * 128 + r) * 256 + kb * 128 + c4 * 4];
            float sc = invn[rb * 128 + r];
            v[0] *= sc; v[1] *= sc; v[2] *= sc; v[3] *= sc;
            unsigned short h0 = f2bf(v[0]), h1 = f2bf(v[1]);
            unsigned short h2 = f2bf(v[2]), h3 = f2bf(v[3]);
            u32x2 pk = { (unsigned)h0 | ((unsigned)h1 << 16),
                         (unsigned)h2 | ((unsigned)h3 << 16) };
            *(u32x2*)&As[r * BKP + c4 * 4] = pk;
        }
        #pragma unroll
        for (int it = 0; it < 8; it++) {
            int flat = tid + it * 256;
            int r = flat >> 4, c8 = flat & 15;
            int gr = (r < 64) ? (cb * 64 + r) : (256 + cb * 64 + (r - 64));
            u32x4 vv = *(const u32x4*)&abt[(size_t)gr * 256 + kb * 128 + c8 * 8];
            *(u32x4*)&Bs[r * BKP + c8 * 8] = vv;
        }
        __syncthreads();
        #pragma unroll
        for (int ks = 0; ks < 4; ks++) {
            const int k0 = ks * 32 + (lane >> 4) * 8;
            s16x8 a[2], b[8];
            #pragma unroll
            for (int tm = 0; tm < 2; tm++)
                a[tm] = *(const s16x8*)&As[(w * 32 + tm * 16 + (lane & 15)) * BKP + k0];
            #pragma unroll
            for (int tn = 0; tn < 8; tn++)
                b[tn] = *(const s16x8*)&Bs[(tn * 16 + (lane & 15)) * BKP + k0];
            #pragma unroll
            for (int tm = 0; tm < 2; tm++)
                #pragma unroll
                for (int tn = 0; tn < 8; tn++)
                    acc[tm * 8 + tn] = __builtin_amdgcn_mfma_f32_16x16x32_bf16(
                        a[tm], b[tn], acc[tm * 8 + tn], 0, 0, 0);
        }
    }

    const int qr = lane >> 4, c = lane & 15;
    #pragma unroll
    for (int tm = 0; tm < 2; tm++) {
        #pragma unroll
        for (int tn = 0; tn < 4; tn++) {
            f32x4 p = acc[tm * 8 + tn];
            f32x4 q = acc[tm * 8 + tn + 4];
            #pragma unroll
            for (int r = 0; r < 4; r++) {
                int m = w * 32 + tm * 16 + qr * 4 + r;
                out[(size_t)(rb * 128 + m) * 256 + cb * 64 + tn * 16 + c] =
                    p[r] * p[r] + q[r] * q[r];
            }
        }
    }
}

// ---------------- host ------------------------------------------------------
extern "C" void kernel_launch(void* const* d_in, const int* in_sizes, int n_in,
                              void* d_out, int out_size, void* d_ws, size_t ws_size,
                              hipStream_t stream) {
    (void)in_sizes; (void)n_in; (void)out_size;
    const float* x      = (const float*)d_in[0];
    const float* rots1  = (const float*)d_in[1];
    const float* phases = (const float*)d_in[2];
    const float* rots2  = (const float*)d_in[3];
    float* out = (float*)d_out;
    char* ws = (char*)d_ws;

    const size_t MAT = 262144;                 // 256x256 fp32
    int pblk = 32;
    while (pblk > 16 &&
           (size_t)3 * pblk * MAT + 2 * MAT + (size_t)BATCH * 512 > ws_size)
        pblk >>= 1;
    const size_t offA   = 0;
    const size_t offB   = offA + (size_t)2 * pblk * MAT;   // A: 2*pblk mats
    const size_t offABT = offB + (size_t)pblk * MAT;       // B: pblk mats
    const size_t offINV = offABT + MAT;
    const size_t offXBF = offINV + MAT;
    const bool use_xbf = (offXBF + (size_t)BATCH * 512) <= ws_size;

    float*          A    = (float*)(ws + offA);
    float*          B    = (float*)(ws + offB);
    unsigned short* abt  = (unsigned short*)(ws + offABT);
    float*          invn = (float*)(ws + offINV);
    unsigned short* xbf  = (unsigned short*)(ws + offXBF);
    // cos/sin table overlays the B ping-pong buffer: written by k_cs, read by
    // k_blocks, dead by the time combine round 1 overwrites B. 522 KB < pblk*MAT.
    float2*         cs   = (float2*)(ws + offB);

    k_cs<<<(2 * NROT) / 256, 256, 0, stream>>>(rots1, rots2, cs);
    k_blocks<<<8 * pblk, 64, 0, stream>>>(cs, A, pblk);

    float* srcp = A; float* dstp = B;
    bool first = true;
    for (int half = pblk / 2; half >= 1; half >>= 1) {
        // round 1 carries 1024 fused xnorm WGs (16 x 64 extra grid.y rows)
        const int xny = (first && use_xbf) ? 64 : 0;
        k_combine<<<dim3(16, 2 * half + xny), 256, 0, stream>>>(srcp, dstp, half, pblk,
                                                                x, xbf);
        float* tmp = srcp; srcp = dstp; dstp = tmp;
        first = false;
    }
    k_abt<<<dim3(16, 2), 256, 0, stream>>>(srcp, phases, abt);

    if (use_xbf) {
        k_gemm_bf<<<dim3(4, BATCH / 128), 256, 0, stream>>>(xbf, abt, out);
    } else {
        k_norm<<<BATCH / 4, 256, 0, stream>>>(x, invn);
        k_gemm_f32<<<dim3(4, BATCH / 128), 256, 0, stream>>>(x, abt, invn, out);
    }
}

// Round 3
// 263.384 us; speedup vs baseline: 1.0412x; 1.0412x over previous
//
#include <hip/hip_runtime.h>
#include <stdint.h>
#include <math.h>

#define NDIM 256
#define BATCH 65536
#define NROT 32640          // 256*255/2

typedef float  f32x4 __attribute__((ext_vector_type(4)));
typedef short  s16x8 __attribute__((ext_vector_type(8)));
typedef unsigned int u32x4 __attribute__((ext_vector_type(4)));
typedef unsigned int u32x2 __attribute__((ext_vector_type(2)));

// round-to-nearest-even float -> bf16 bits
static __device__ __forceinline__ unsigned short f2bf(float f) {
    unsigned int u = __float_as_uint(f);
    u += 0x7fffu + ((u >> 16) & 1u);
    return (unsigned short)(u >> 16);
}
static __device__ __forceinline__ float bf2f(unsigned short h) {
    return __uint_as_float(((unsigned)h) << 16);
}

// split 4 fp32 -> bf16 hi + bf16 lo (packed).  a ~= hi + lo, |err| ~ 2^-18|a|
static __device__ __forceinline__ void split4(f32x4 v, u32x2* hi, u32x2* lo) {
    unsigned short h[4], l[4];
    #pragma unroll
    for (int i = 0; i < 4; i++) {
        h[i] = f2bf(v[i]);
        l[i] = f2bf(v[i] - bf2f(h[i]));
    }
    *hi = (u32x2){ (unsigned)h[0] | ((unsigned)h[1] << 16),
                   (unsigned)h[2] | ((unsigned)h[3] << 16) };
    *lo = (u32x2){ (unsigned)l[0] | ((unsigned)l[1] << 16),
                   (unsigned)l[2] | ((unsigned)l[3] << 16) };
}
static __device__ __forceinline__ void split8(const float* v, u32x4* hi, u32x4* lo) {
    unsigned short h[8], l[8];
    #pragma unroll
    for (int i = 0; i < 8; i++) {
        h[i] = f2bf(v[i]);
        l[i] = f2bf(v[i] - bf2f(h[i]));
    }
    *hi = (u32x4){ (unsigned)h[0] | ((unsigned)h[1] << 16),
                   (unsigned)h[2] | ((unsigned)h[3] << 16),
                   (unsigned)h[4] | ((unsigned)h[5] << 16),
                   (unsigned)h[6] | ((unsigned)h[7] << 16) };
    *lo = (u32x4){ (unsigned)l[0] | ((unsigned)l[1] << 16),
                   (unsigned)l[2] | ((unsigned)l[3] << 16),
                   (unsigned)l[4] | ((unsigned)l[5] << 16),
                   (unsigned)l[6] | ((unsigned)l[7] << 16) };
}

// nearest 4-aligned sweep boundary to k*(NROT/pblk); shared by k_blocks
// and k_combine (the block-diagonal skip logic depends on agreement).
static __device__ __forceinline__ int sweep_bound(int k, int pblk) {
    int target = k * (NROT / pblk);
    int best = 0, bd = 0x7fffffff;
    for (int i = 0; i <= 256; i += 4) {
        int pre = i * 255 - (i * (i - 1)) / 2;
        int d = pre - target; d = (d < 0) ? -d : d;
        if (d < bd) { bd = d; best = i; }
    }
    return best;
}

// ---------------- kernel 0: angle table (cos,sin) for both rot sets ---------
__global__ __launch_bounds__(256) void k_cs(const float* __restrict__ r1,
                                            const float* __restrict__ r2,
                                            float2* __restrict__ cs) {
    int i = blockIdx.x * 256 + threadIdx.x;          // 0 .. 2*NROT-1
    float th = (i < NROT) ? r1[i] : r2[i - NROT];
    float sv, cv; sincosf(th, &sv, &cv);
    cs[i] = make_float2(cv, sv);
}

// ---------------- kernel 1: build pblk partial Givens products per matrix ---
// Latency-bound single-wave WGs (1/CU). R2 evidence: wave ~90% stalled, VALU
// issue is NOT the limit -> this version software-pipelines every long-latency
// access in registers:
//   - abuf: 8-deep angle prefetch (mirrors rbuf) so all LDS reads of unroll
//     body n+1 are issued during body n's compute (angles are wave-uniform ->
//     broadcast reads, conflict-free).
//   - group staging split issue-early/commit-late with double-buffered csb:
//     group g+1's 16 global float2 loads are issued BEFORE group g's j-loop
//     (L2 latency hides under it), committed to LDS after.
__global__ __launch_bounds__(64) void k_blocks(const float2* __restrict__ cs,
                                               float* __restrict__ bmats, int pblk) {
    __shared__ float colb[264 * 64];
    __shared__ float2 csb[2][256 * 4];  // double-buffered steady angles
    __shared__ float2 tri[24 * 6];      // all groups' triangle angles

    const int t = threadIdx.x;          // column within chunk
    const int bid = blockIdx.x;
    const int chunk = bid & 3;          // 0..3 (64 cols each)
    const int b = (bid >> 2) % pblk;    // 0..pblk-1
    const int set = (bid >> 2) / pblk;  // 0 = rots1, 1 = rots2
    const int col0 = chunk * 64;
    const float2* cst = cs + (size_t)set * NROT;

    const int s0 = sweep_bound(b, pblk);
    const int s1 = sweep_bound(b + 1, pblk);
    const int ngroups = (s1 - s0) >> 2;

    // zero colb (incl. pad rows 256..263), set identity diagonal
    {
        const f32x4 z = {0.f, 0.f, 0.f, 0.f};
        #pragma unroll 11
        for (int q = 0; q < 66; q++)
            *(f32x4*)&colb[(q * 64 + t) * 4] = z;
        colb[(col0 + t) * 64 + t] = 1.0f;
    }

    // stage all triangle angles (6 per group) into LDS
    for (int k = t; k < ngroups * 6; k += 64) {
        int g = k / 6, q = k - g * 6;
        int a  = (q < 3) ? 0 : ((q < 5) ? 1 : 2);
        int bb = (q < 3) ? (q + 1) : ((q < 5) ? (q - 1) : 3);
        int m0 = s0 + g * 4;
        int m = m0 + a;
        int base = m * 255 - (m * (m - 1)) / 2;
        tri[k] = cst[base - m - 1 + m0 + bb];
    }
    // single-wave WG: DS pipe is in-order per wave, no barrier needed

    float2 gv[16];                      // in-flight staging registers
    // issue+commit group 0 staging
    {
        const int m0g = s0;
        int offg[4];
        #pragma unroll
        for (int a = 0; a < 4; a++) {
            int m = m0g + a;
            offg[a] = m * 255 - (m * (m - 1)) / 2 - m - 1;
        }
        #pragma unroll
        for (int it = 0; it < 16; it++) {
            int k = t + it * 64;
            int jj = k >> 2, a = k & 3;
            int j = m0g + 4 + jj;
            gv[it] = (j < 256) ? cst[offg[a] + j] : make_float2(1.f, 0.f);
        }
        #pragma unroll
        for (int it = 0; it < 16; it++)
            csb[0][t + it * 64] = gv[it];
    }

    for (int g = 0; g < ngroups; g++) {
        const int m0 = s0 + g * 4;
        const int buf = g & 1;
        const int n_j = 252 - m0;
        const int n_p = (n_j > 0) ? ((n_j + 7) & ~7) : 0;
        const float* csbuf = (const float*)&csb[buf][0];

        // issue NEXT group's staging loads (latency hides under this j-loop)
        const bool have_next = (g + 1 < ngroups);
        if (have_next) {
            const int m0g = m0 + 4;
            int offg[4];
            #pragma unroll
            for (int a = 0; a < 4; a++) {
                int m = m0g + a;
                offg[a] = m * 255 - (m * (m - 1)) / 2 - m - 1;
            }
            #pragma unroll
            for (int it = 0; it < 16; it++) {
                int k = t + it * 64;
                int jj = k >> 2, a = k & 3;
                int j = m0g + 4 + jj;
                gv[it] = (j < 256) ? cst[offg[a] + j] : make_float2(1.f, 0.f);
            }
        }

        // active rows -> registers
        float u0 = colb[(m0 + 0) * 64 + t];
        float u1 = colb[(m0 + 1) * 64 + t];
        float u2 = colb[(m0 + 2) * 64 + t];
        float u3 = colb[(m0 + 3) * 64 + t];

        // triangle peel: (m0,m0+1..3), (m0+1,m0+2..3), (m0+2,m0+3)
        {
            float2 cv; float nr;
            cv = tri[g * 6 + 0]; nr = cv.y * u0 + cv.x * u1; u0 = cv.x * u0 - cv.y * u1; u1 = nr;
            cv = tri[g * 6 + 1]; nr = cv.y * u0 + cv.x * u2; u0 = cv.x * u0 - cv.y * u2; u2 = nr;
            cv = tri[g * 6 + 2]; nr = cv.y * u0 + cv.x * u3; u0 = cv.x * u0 - cv.y * u3; u3 = nr;
            cv = tri[g * 6 + 3]; nr = cv.y * u1 + cv.x * u2; u1 = cv.x * u1 - cv.y * u2; u2 = nr;
            cv = tri[g * 6 + 4]; nr = cv.y * u1 + cv.x * u3; u1 = cv.x * u1 - cv.y * u3; u3 = nr;
            cv = tri[g * 6 + 5]; nr = cv.y * u2 + cv.x * u3; u2 = cv.x * u2 - cv.y * u3; u3 = nr;
        }

        // steady state: guard-free, unroll 8, 8-deep row AND angle prefetch
        if (n_p > 0) {
            float rbuf[8];
            f32x4 abuf[8][2];           // [p][0]={a0,a1}, [p][1]={a2,a3}
            #pragma unroll
            for (int p = 0; p < 8; p++) {
                rbuf[p] = colb[(m0 + 4 + p) * 64 + t];
                abuf[p][0] = *(const f32x4*)&csbuf[p * 8 + 0];
                abuf[p][1] = *(const f32x4*)&csbuf[p * 8 + 4];
            }
            for (int c = 0; c < n_p; c += 8) {
                #pragma unroll
                for (int p = 0; p < 8; p++) {
                    const int j = m0 + 4 + c + p;
                    float r = rbuf[p];
                    f32x4 A01 = abuf[p][0], A23 = abuf[p][1];
                    int jn = j + 8; jn = (jn < 263) ? jn : 263;
                    int cn = c + p + 8; cn = (cn < n_p) ? cn : (n_p - 1);
                    rbuf[p] = colb[jn * 64 + t];
                    abuf[p][0] = *(const f32x4*)&csbuf[cn * 8 + 0];
                    abuf[p][1] = *(const f32x4*)&csbuf[cn * 8 + 4];
                    float nr;
                    nr = A01[1] * u0 + A01[0] * r; u0 = A01[0] * u0 - A01[1] * r; r = nr;
                    nr = A01[3] * u1 + A01[2] * r; u1 = A01[2] * u1 - A01[3] * r; r = nr;
                    nr = A23[1] * u2 + A23[0] * r; u2 = A23[0] * u2 - A23[1] * r; r = nr;
                    nr = A23[3] * u3 + A23[2] * r; u3 = A23[2] * u3 - A23[3] * r; r = nr;
                    colb[j * 64 + t] = r;
                }
            }
        }
        colb[(m0 + 0) * 64 + t] = u0;
        colb[(m0 + 1) * 64 + t] = u1;
        colb[(m0 + 2) * 64 + t] = u2;
        colb[(m0 + 3) * 64 + t] = u3;

        // commit next group's staged angles to the other csb buffer
        if (have_next) {
            #pragma unroll
            for (int it = 0; it < 16; it++)
                csb[buf ^ 1][t + it * 64] = gv[it];
        }
    }

    float* outm = bmats + (size_t)(set * pblk + b) * 65536;
    for (int r = 0; r < 256; r++)
        outm[(size_t)r * 256 + col0 + t] = colb[r * 64 + t];
}

// ---------------- kernel 2: pairwise combine round (bf16x3 MFMA matmul) -----
// dst[p] = src[2p+1] @ src[2p], fp32 in/out, computed as
// D = Ahi*Bhi + Ahi*Blo + Alo*Bhi with fp32 MFMA accumulators.
// Round 1 additionally carries the xnorm WGs (blockIdx.y >= 2*half).
__global__ __launch_bounds__(256) void k_combine(const float* __restrict__ src,
                                                 float* __restrict__ dst,
                                                 int half, int pblk,
                                                 const float* __restrict__ xg,
                                                 unsigned short* __restrict__ xbf) {
    const int by = blockIdx.y;
    const int tid = threadIdx.x;

    if (by >= 2 * half) {                      // ---- fused xnorm WGs ----
        const int id = (by - 2 * half) * 16 + blockIdx.x;   // 0..1023
        const int w = tid >> 6, lane = tid & 63;
        const int r0 = id * 64;
        #pragma unroll 2
        for (int p = 0; p < 16; p++) {
            int row = r0 + p * 4 + w;
            f32x4 v = *(const f32x4*)&xg[(size_t)row * 256 + lane * 4];
            float s = v[0] * v[0] + v[1] * v[1] + v[2] * v[2] + v[3] * v[3];
            #pragma unroll
            for (int off = 32; off; off >>= 1) s += __shfl_xor(s, off, 64);
            float sc = 1.0f / sqrtf(s);
            unsigned short h0 = f2bf(v[0] * sc), h1 = f2bf(v[1] * sc);
            unsigned short h2 = f2bf(v[2] * sc), h3 = f2bf(v[3] * sc);
            u32x2 pk = { (unsigned)h0 | ((unsigned)h1 << 16),
                         (unsigned)h2 | ((unsigned)h3 << 16) };
            *(u32x2*)&xbf[(size_t)row * 256 + lane * 4] = pk;
        }
        return;
    }

    const int set = by / half, pidx = by % half;
    const int stride = pblk / (2 * half);
    const int s0A = sweep_bound((2 * pidx + 1) * stride, pblk);
    const float* Am = src + (size_t)(set * 2 * half + 2 * pidx + 1) * 65536;
    const float* Bm = src + (size_t)(set * 2 * half + 2 * pidx) * 65536;
    float* Dm = dst + (size_t)(set * half + pidx) * 65536;
    const int tr = blockIdx.x >> 2, tc = blockIdx.x & 3;

    if (tr * 64 + 64 <= s0A) {                 // pure copy tile: D = B
        #pragma unroll
        for (int it = 0; it < 4; it++) {
            int flat = tid + it * 256;
            int r = flat >> 4, c4 = flat & 15;
            size_t idx = (size_t)(tr * 64 + r) * 256 + tc * 64 + c4 * 4;
            *(f32x4*)&Dm[idx] = *(const f32x4*)&Bm[idx];
        }
        return;
    }
    const int kb0 = (tr * 64 >= s0A) ? (s0A >> 5) : 0;

    __shared__ unsigned short Ahi[64 * 40], Alo[64 * 40];
    __shared__ unsigned short Bhi[64 * 40], Blo[64 * 40];

    const int lane = tid & 63, w = tid >> 6;
    const int mh = (w >> 1) * 32, nh = (w & 1) * 32;
    const int l15 = lane & 15, lq = lane >> 4;
    const int bn = tid & 63, bkq = tid >> 6;   // B transpose-stage mapping

    f32x4 acc[2][2];
    #pragma unroll
    for (int i = 0; i < 2; i++)
        #pragma unroll
        for (int j = 0; j < 2; j++) acc[i][j] = (f32x4){0.f, 0.f, 0.f, 0.f};

    for (int kb = kb0; kb < 8; kb++) {
        __syncthreads();
        // A stage: 64 rows x 32 k, natural k-minor layout
        #pragma unroll
        for (int it = 0; it < 2; it++) {
            int flat = tid + it * 256;
            int r = flat >> 3, c4 = flat & 7;
            f32x4 v = *(const f32x4*)&Am[(size_t)(tr * 64 + r) * 256 + kb * 32 + c4 * 4];
            u32x2 hi, lo; split4(v, &hi, &lo);
            *(u32x2*)&Ahi[r * 40 + c4 * 4] = hi;
            *(u32x2*)&Alo[r * 40 + c4 * 4] = lo;
        }
        // B stage: transpose [32k][64n] -> [64n][32k] via coalesced re-reads
        {
            float bv[8];
            #pragma unroll
            for (int i = 0; i < 8; i++)
                bv[i] = Bm[(size_t)(kb * 32 + bkq * 8 + i) * 256 + tc * 64 + bn];
            u32x4 hi, lo; split8(bv, &hi, &lo);
            *(u32x4*)&Bhi[bn * 40 + bkq * 8] = hi;
            *(u32x4*)&Blo[bn * 40 + bkq * 8] = lo;
        }
        __syncthreads();
        s16x8 ah[2], al[2], bh[2], bl[2];
        #pragma unroll
        for (int tm = 0; tm < 2; tm++) {
            ah[tm] = *(const s16x8*)&Ahi[(mh + tm * 16 + l15) * 40 + lq * 8];
            al[tm] = *(const s16x8*)&Alo[(mh + tm * 16 + l15) * 40 + lq * 8];
        }
        #pragma unroll
        for (int tn = 0; tn < 2; tn++) {
            bh[tn] = *(const s16x8*)&Bhi[(nh + tn * 16 + l15) * 40 + lq * 8];
            bl[tn] = *(const s16x8*)&Blo[(nh + tn * 16 + l15) * 40 + lq * 8];
        }
        #pragma unroll
        for (int tm = 0; tm < 2; tm++)
            #pragma unroll
            for (int tn = 0; tn < 2; tn++) {
                acc[tm][tn] = __builtin_amdgcn_mfma_f32_16x16x32_bf16(ah[tm], bh[tn], acc[tm][tn], 0, 0, 0);
                acc[tm][tn] = __builtin_amdgcn_mfma_f32_16x16x32_bf16(ah[tm], bl[tn], acc[tm][tn], 0, 0, 0);
                acc[tm][tn] = __builtin_amdgcn_mfma_f32_16x16x32_bf16(al[tm], bh[tn], acc[tm][tn], 0, 0, 0);
            }
    }
    // epilogue: C/D layout col = lane&15, row = (lane>>4)*4 + reg
    #pragma unroll
    for (int tm = 0; tm < 2; tm++)
        #pragma unroll
        for (int tn = 0; tn < 2; tn++)
            #pragma unroll
            for (int r = 0; r < 4; r++)
                Dm[(size_t)(tr * 64 + mh + tm * 16 + lq * 4 + r) * 256
                   + tc * 64 + nh + tn * 16 + l15] = acc[tm][tn][r];
}

// ---------------- kernel 3: AT/BT = M2 @ diag(cos|sin(phases)) @ M1 -> bf16 -
__global__ __launch_bounds__(256) void k_abt(const float* __restrict__ mats,
                                             const float* __restrict__ phases,
                                             unsigned short* __restrict__ abt) {
    const float* Am = mats + 65536;    // M2
    const float* Bm = mats;            // M1
    const int v = blockIdx.y;          // 0: cos (AT), 1: sin (BT)
    const int tr = blockIdx.x >> 2, tc = blockIdx.x & 3;
    const int tid = threadIdx.x;

    __shared__ unsigned short Ahi[64 * 40], Alo[64 * 40];
    __shared__ unsigned short Bhi[64 * 40], Blo[64 * 40];

    const int lane = tid & 63, w = tid >> 6;
    const int mh = (w >> 1) * 32, nh = (w & 1) * 32;
    const int l15 = lane & 15, lq = lane >> 4;
    const int bn = tid & 63, bkq = tid >> 6;

    f32x4 acc[2][2];
    #pragma unroll
    for (int i = 0; i < 2; i++)
        #pragma unroll
        for (int j = 0; j < 2; j++) acc[i][j] = (f32x4){0.f, 0.f, 0.f, 0.f};

    for (int kb = 0; kb < 8; kb++) {
        __syncthreads();
        #pragma unroll
        for (int it = 0; it < 2; it++) {
            int flat = tid + it * 256;
            int r = flat >> 3, c4 = flat & 7;
            f32x4 vv = *(const f32x4*)&Am[(size_t)(tr * 64 + r) * 256 + kb * 32 + c4 * 4];
            u32x2 hi, lo; split4(vv, &hi, &lo);
            *(u32x2*)&Ahi[r * 40 + c4 * 4] = hi;
            *(u32x2*)&Alo[r * 40 + c4 * 4] = lo;
        }
        {
            float bv[8];
            #pragma unroll
            for (int i = 0; i < 8; i++) {
                int kg = kb * 32 + bkq * 8 + i;          // wave-uniform k index
                float ph = phases[kg];
                float sc = v ? sinf(ph) : cosf(ph);
                bv[i] = Bm[(size_t)kg * 256 + tc * 64 + bn] * sc;
            }
            u32x4 hi, lo; split8(bv, &hi, &lo);
            *(u32x4*)&Bhi[bn * 40 + bkq * 8] = hi;
            *(u32x4*)&Blo[bn * 40 + bkq * 8] = lo;
        }
        __syncthreads();
        s16x8 ah[2], al[2], bh[2], bl[2];
        #pragma unroll
        for (int tm = 0; tm < 2; tm++) {
            ah[tm] = *(const s16x8*)&Ahi[(mh + tm * 16 + l15) * 40 + lq * 8];
            al[tm] = *(const s16x8*)&Alo[(mh + tm * 16 + l15) * 40 + lq * 8];
        }
        #pragma unroll
        for (int tn = 0; tn < 2; tn++) {
            bh[tn] = *(const s16x8*)&Bhi[(nh + tn * 16 + l15) * 40 + lq * 8];
            bl[tn] = *(const s16x8*)&Blo[(nh + tn * 16 + l15) * 40 + lq * 8];
        }
        #pragma unroll
        for (int tm = 0; tm < 2; tm++)
            #pragma unroll
            for (int tn = 0; tn < 2; tn++) {
                acc[tm][tn] = __builtin_amdgcn_mfma_f32_16x16x32_bf16(ah[tm], bh[tn], acc[tm][tn], 0, 0, 0);
                acc[tm][tn] = __builtin_amdgcn_mfma_f32_16x16x32_bf16(ah[tm], bl[tn], acc[tm][tn], 0, 0, 0);
                acc[tm][tn] = __builtin_amdgcn_mfma_f32_16x16x32_bf16(al[tm], bh[tn], acc[tm][tn], 0, 0, 0);
            }
    }
    #pragma unroll
    for (int tm = 0; tm < 2; tm++)
        #pragma unroll
        for (int tn = 0; tn < 2; tn++)
            #pragma unroll
            for (int r = 0; r < 4; r++)
                abt[(size_t)(v * 256 + tr * 64 + mh + tm * 16 + lq * 4 + r) * 256
                    + tc * 64 + nh + tn * 16 + l15] = f2bf(acc[tm][tn][r]);
}

// ---------------- kernel 4b: per-row 1/||x|| (fallback path) ----------------
__global__ __launch_bounds__(256) void k_norm(const float* __restrict__ x,
                                              float* __restrict__ invn) {
    const int row = blockIdx.x * 4 + (threadIdx.x >> 6);
    const int lane = threadIdx.x & 63;
    f32x4 v = *(const f32x4*)&x[(size_t)row * 256 + lane * 4];
    float s = v[0] * v[0] + v[1] * v[1] + v[2] * v[2] + v[3] * v[3];
    for (int off = 32; off; off >>= 1) s += __shfl_xor(s, off, 64);
    if (lane == 0) invn[row] = 1.0f / sqrtf(s);
}

// ---------------- kernel 5a: GEMM + |.|^2 from pre-converted bf16 x ---------
// XCD swizzle: launched order is x-major and WG->XCD is round-robin, so the
// 4 cb WGs sharing an x-tile would land on 4 different XCD L2s. Remap
// l=(y*4+x) -> L=(l&7)*256+(l>>3): each XCD gets 64 contiguous rb x all 4 cb
// -> x-tile fetched once per XCD (4 MB/XCD = L2-sized), abt replicated (256KB).
#define BKP 136   // padded LDS k-stride (bf16 elems)
__global__ __launch_bounds__(256) void k_gemm_bf(const unsigned short* __restrict__ xbf,
                                                 const unsigned short* __restrict__ abt,
                                                 float* __restrict__ out) {
    __shared__ unsigned short As[128 * BKP];
    __shared__ unsigned short Bs[128 * BKP];
    const int tid = threadIdx.x;
    const int l  = blockIdx.y * 4 + blockIdx.x;
    const int L  = (l & 7) * 256 + (l >> 3);
    const int cb = L & 3;               // 0..3  (64 out-cols each)
    const int rb = L >> 2;              // 0..511
    const int lane = tid & 63, w = tid >> 6;

    f32x4 acc[16];
    #pragma unroll
    for (int i = 0; i < 16; i++) acc[i] = (f32x4){0.f, 0.f, 0.f, 0.f};

    int rA[8], cA[8], grB[8];
    #pragma unroll
    for (int it = 0; it < 8; it++) {
        int flat = tid + it * 256;
        rA[it] = flat >> 4; cA[it] = flat & 15;
        int r = rA[it];
        grB[it] = (r < 64) ? (cb * 64 + r) : (256 + cb * 64 + (r - 64));
    }

    u32x4 pa[8], pb[8];
    #pragma unroll
    for (int it = 0; it < 8; it++) {
        pa[it] = *(const u32x4*)&xbf[(size_t)(rb * 128 + rA[it]) * 256 + cA[it] * 8];
        pb[it] = *(const u32x4*)&abt[(size_t)grB[it] * 256 + cA[it] * 8];
    }
    #pragma unroll
    for (int it = 0; it < 8; it++) {
        *(u32x4*)&As[rA[it] * BKP + cA[it] * 8] = pa[it];
        *(u32x4*)&Bs[rA[it] * BKP + cA[it] * 8] = pb[it];
    }
    __syncthreads();
    #pragma unroll
    for (int it = 0; it < 8; it++) {
        pa[it] = *(const u32x4*)&xbf[(size_t)(rb * 128 + rA[it]) * 256 + 128 + cA[it] * 8];
        pb[it] = *(const u32x4*)&abt[(size_t)grB[it] * 256 + 128 + cA[it] * 8];
    }

    auto compute = [&]() {
        #pragma unroll
        for (int ks = 0; ks < 4; ks++) {
            const int k0 = ks * 32 + (lane >> 4) * 8;
            s16x8 a[2], b[8];
            #pragma unroll
            for (int tm = 0; tm < 2; tm++)
                a[tm] = *(const s16x8*)&As[(w * 32 + tm * 16 + (lane & 15)) * BKP + k0];
            #pragma unroll
            for (int tn = 0; tn < 8; tn++)
                b[tn] = *(const s16x8*)&Bs[(tn * 16 + (lane & 15)) * BKP + k0];
            #pragma unroll
            for (int tm = 0; tm < 2; tm++)
                #pragma unroll
                for (int tn = 0; tn < 8; tn++)
                    acc[tm * 8 + tn] = __builtin_amdgcn_mfma_f32_16x16x32_bf16(
                        a[tm], b[tn], acc[tm * 8 + tn], 0, 0, 0);
        }
    };
    compute();                 // kb=0
    __syncthreads();
    #pragma unroll
    for (int it = 0; it < 8; it++) {
        *(u32x4*)&As[rA[it] * BKP + cA[it] * 8] = pa[it];
        *(u32x4*)&Bs[rA[it] * BKP + cA[it] * 8] = pb[it];
    }
    __syncthreads();
    compute();                 // kb=1

    const int qr = lane >> 4, c = lane & 15;
    #pragma unroll
    for (int tm = 0; tm < 2; tm++) {
        #pragma unroll
        for (int tn = 0; tn < 4; tn++) {
            f32x4 p = acc[tm * 8 + tn];
            f32x4 q = acc[tm * 8 + tn + 4];
            #pragma unroll
            for (int r = 0; r < 4; r++) {
                int m = w * 32 + tm * 16 + qr * 4 + r;
                out[(size_t)(rb * 128 + m) * 256 + cb * 64 + tn * 16 + c] =
                    p[r] * p[r] + q[r] * q[r];
            }
        }
    }
}

// ---------------- kernel 5b: GEMM + |.|^2 from fp32 x (fallback) ------------
__global__ __launch_bounds__(256) void k_gemm_f32(const float* __restrict__ x,
                                                  const unsigned short* __restrict__ abt,
                                                  const float* __restrict__ invn,
                                                  float* __restrict__ out) {
    __shared__ unsigned short As[128 * BKP];
    __shared__ unsigned short Bs[128 * BKP];
    const int tid = threadIdx.x;
    const int l  = blockIdx.y * 4 + blockIdx.x;
    const int L  = (l & 7) * 256 + (l >> 3);
    const int cb = L & 3;
    const int rb = L >> 2;
    const int lane = tid & 63, w = tid >> 6;

    f32x4 acc[16];
    #pragma unroll
    for (int i = 0; i < 16; i++) acc[i] = (f32x4){0.f, 0.f, 0.f, 0.f};

    for (int kb = 0; kb < 2; kb++) {
        __syncthreads();
        #pragma unroll
        for (int it = 0; it < 16; it++) {
            int flat = tid + it * 256;
            int r = flat >> 5, c4 = flat & 31;
            f32x4 v = *(const f32x4*)&x[(size_t)(rb * 128 + r) * 256 + kb * 128 + c4 * 4];
            float sc = invn[rb * 128 + r];
            v[0] *= sc; v[1] *= sc; v[2] *= sc; v[3] *= sc;
            unsigned short h0 = f2bf(v[0]), h1 = f2bf(v[1]);
            unsigned short h2 = f2bf(v[2]), h3 = f2bf(v[3]);
            u32x2 pk = { (unsigned)h0 | ((unsigned)h1 << 16),
                         (unsigned)h2 | ((unsigned)h3 << 16) };
            *(u32x2*)&As[r * BKP + c4 * 4] = pk;
        }
        #pragma unroll
        for (int it = 0; it < 8; it++) {
            int flat = tid + it * 256;
            int r = flat >> 4, c8 = flat & 15;
            int gr = (r < 64) ? (cb * 64 + r) : (256 + cb * 64 + (r - 64));
            u32x4 vv = *(const u32x4*)&abt[(size_t)gr * 256 + kb * 128 + c8 * 8];
            *(u32x4*)&Bs[r * BKP + c8 * 8] = vv;
        }
        __syncthreads();
        #pragma unroll
        for (int ks = 0; ks < 4; ks++) {
            const int k0 = ks * 32 + (lane >> 4) * 8;
            s16x8 a[2], b[8];
            #pragma unroll
            for (int tm = 0; tm < 2; tm++)
                a[tm] = *(const s16x8*)&As[(w * 32 + tm * 16 + (lane & 15)) * BKP + k0];
            #pragma unroll
            for (int tn = 0; tn < 8; tn++)
                b[tn] = *(const s16x8*)&Bs[(tn * 16 + (lane & 15)) * BKP + k0];
            #pragma unroll
            for (int tm = 0; tm < 2; tm++)
                #pragma unroll
                for (int tn = 0; tn < 8; tn++)
                    acc[tm * 8 + tn] = __builtin_amdgcn_mfma_f32_16x16x32_bf16(
                        a[tm], b[tn], acc[tm * 8 + tn], 0, 0, 0);
        }
    }

    const int qr = lane >> 4, c = lane & 15;
    #pragma unroll
    for (int tm = 0; tm < 2; tm++) {
        #pragma unroll
        for (int tn = 0; tn < 4; tn++) {
            f32x4 p = acc[tm * 8 + tn];
            f32x4 q = acc[tm * 8 + tn + 4];
            #pragma unroll
            for (int r = 0; r < 4; r++) {
                int m = w * 32 + tm * 16 + qr * 4 + r;
                out[(size_t)(rb * 128 + m) * 256 + cb * 64 + tn * 16 + c] =
                    p[r] * p[r] + q[r] * q[r];
            }
        }
    }
}

// ---------------- host ------------------------------------------------------
extern "C" void kernel_launch(void* const* d_in, const int* in_sizes, int n_in,
                              void* d_out, int out_size, void* d_ws, size_t ws_size,
                              hipStream_t stream) {
    (void)in_sizes; (void)n_in; (void)out_size;
    const float* x      = (const float*)d_in[0];
    const float* rots1  = (const float*)d_in[1];
    const float* phases = (const float*)d_in[2];
    const float* rots2  = (const float*)d_in[3];
    float* out = (float*)d_out;
    char* ws = (char*)d_ws;

    const size_t MAT = 262144;                 // 256x256 fp32
    int pblk = 32;
    while (pblk > 16 &&
           (size_t)3 * pblk * MAT + 2 * MAT + (size_t)BATCH * 512 > ws_size)
        pblk >>= 1;
    const size_t offA   = 0;
    const size_t offB   = offA + (size_t)2 * pblk * MAT;   // A: 2*pblk mats
    const size_t offABT = offB + (size_t)pblk * MAT;       // B: pblk mats
    const size_t offINV = offABT + MAT;
    const size_t offXBF = offINV + MAT;
    const bool use_xbf = (offXBF + (size_t)BATCH * 512) <= ws_size;

    float*          A    = (float*)(ws + offA);
    float*          B    = (float*)(ws + offB);
    unsigned short* abt  = (unsigned short*)(ws + offABT);
    float*          invn = (float*)(ws + offINV);
    unsigned short* xbf  = (unsigned short*)(ws + offXBF);
    // cos/sin table overlays the B ping-pong buffer: written by k_cs, read by
    // k_blocks, dead by the time combine round 1 overwrites B. 522 KB < pblk*MAT.
    float2*         cs   = (float2*)(ws + offB);

    k_cs<<<(2 * NROT) / 256, 256, 0, stream>>>(rots1, rots2, cs);
    k_blocks<<<8 * pblk, 64, 0, stream>>>(cs, A, pblk);

    float* srcp = A; float* dstp = B;
    bool first = true;
    for (int half = pblk / 2; half >= 1; half >>= 1) {
        // round 1 carries 1024 fused xnorm WGs (16 x 64 extra grid.y rows)
        const int xny = (first && use_xbf) ? 64 : 0;
        k_combine<<<dim3(16, 2 * half + xny), 256, 0, stream>>>(srcp, dstp, half, pblk,
                                                                x, xbf);
        float* tmp = srcp; srcp = dstp; dstp = tmp;
        first = false;
    }
    k_abt<<<dim3(16, 2), 256, 0, stream>>>(srcp, phases, abt);

    if (use_xbf) {
        k_gemm_bf<<<dim3(4, BATCH / 128), 256, 0, stream>>>(xbf, abt, out);
    } else {
        k_norm<<<BATCH / 4, 256, 0, stream>>>(x, invn);
        k_gemm_f32<<<dim3(4, BATCH / 128), 256, 0, stream>>>(x, abt, invn, out);
    }
}